// Round 1
// baseline (10620.509 us; speedup 1.0000x reference)
//
#include <hip/hip_runtime.h>

#define CIN 256
#define NGROUPS 16
#define GN_EPS 1e-5f
#define NCLS 80
#define TPOINTS 17064

// ---------------------------------------------------------------------------
// Tower conv: 3x3, SAME, 256->256, fused bias + GN partial stats (sum, sumsq).
// Block: 256 threads = 256 spatial positions. Each thread computes 4 output
// channels (co0..co0+3, all within one GN group since co0 % 4 == 0 and group
// size 16). Weights are block-uniform -> scalar loads feed v_fma s-operands.
// ---------------------------------------------------------------------------
__global__ __launch_bounds__(256) void conv_tower_k(
    const float* __restrict__ x,     // [N,256,H,W]
    const float* __restrict__ w,     // [256,256,3,3]
    const float* __restrict__ bias,  // [256]
    float* __restrict__ y,           // [N,256,H,W]
    float* __restrict__ stats,       // [N*16*2] (sum, sumsq)
    int H, int lw)
{
    const int W = 1 << lw;
    const int HW = H << lw;
    const int tid = threadIdx.x;
    const int p = blockIdx.x * 256 + tid;
    const int co0 = blockIdx.y * 4;
    const int n = blockIdx.z;

    float acc0 = 0.f, acc1 = 0.f, acc2 = 0.f, acc3 = 0.f;
    const bool active = p < HW;

    if (active) {
        const int h = p >> lw;
        const int wc = p & (W - 1);
        const bool tok = h > 0, bok = h < H - 1;
        const bool lok = wc > 0, rok = wc < W - 1;
        const float* xn = x + (size_t)n * CIN * HW + p;
        const float* wq = w + (size_t)co0 * (CIN * 9);

        for (int ci = 0; ci < CIN; ++ci) {
            const float* xc = xn + ci * HW;
            float x00 = (tok & lok) ? xc[-W - 1] : 0.f;
            float x01 = tok ? xc[-W] : 0.f;
            float x02 = (tok & rok) ? xc[-W + 1] : 0.f;
            float x10 = lok ? xc[-1] : 0.f;
            float x11 = xc[0];
            float x12 = rok ? xc[1] : 0.f;
            float x20 = (bok & lok) ? xc[W - 1] : 0.f;
            float x21 = bok ? xc[W] : 0.f;
            float x22 = (bok & rok) ? xc[W + 1] : 0.f;

            const float* w0 = wq + ci * 9;
            const float* w1 = w0 + CIN * 9;
            const float* w2 = w1 + CIN * 9;
            const float* w3 = w2 + CIN * 9;
            acc0 += x00*w0[0] + x01*w0[1] + x02*w0[2] + x10*w0[3] + x11*w0[4]
                  + x12*w0[5] + x20*w0[6] + x21*w0[7] + x22*w0[8];
            acc1 += x00*w1[0] + x01*w1[1] + x02*w1[2] + x10*w1[3] + x11*w1[4]
                  + x12*w1[5] + x20*w1[6] + x21*w1[7] + x22*w1[8];
            acc2 += x00*w2[0] + x01*w2[1] + x02*w2[2] + x10*w2[3] + x11*w2[4]
                  + x12*w2[5] + x20*w2[6] + x21*w2[7] + x22*w2[8];
            acc3 += x00*w3[0] + x01*w3[1] + x02*w3[2] + x10*w3[3] + x11*w3[4]
                  + x12*w3[5] + x20*w3[6] + x21*w3[7] + x22*w3[8];
        }
        acc0 += bias[co0 + 0];
        acc1 += bias[co0 + 1];
        acc2 += bias[co0 + 2];
        acc3 += bias[co0 + 3];
        float* yn = y + (size_t)n * CIN * HW + p;
        yn[(size_t)(co0 + 0) * HW] = acc0;
        yn[(size_t)(co0 + 1) * HW] = acc1;
        yn[(size_t)(co0 + 2) * HW] = acc2;
        yn[(size_t)(co0 + 3) * HW] = acc3;
    }

    // GN partial stats over (bias-added) conv outputs
    float s  = active ? (acc0 + acc1 + acc2 + acc3) : 0.f;
    float ss = active ? (acc0*acc0 + acc1*acc1 + acc2*acc2 + acc3*acc3) : 0.f;
#pragma unroll
    for (int off = 32; off > 0; off >>= 1) {
        s  += __shfl_down(s, off, 64);
        ss += __shfl_down(ss, off, 64);
    }
    __shared__ float ls[8];
    const int lane = tid & 63, wv = tid >> 6;
    if (lane == 0) { ls[wv * 2] = s; ls[wv * 2 + 1] = ss; }
    __syncthreads();
    if (tid == 0) {
        float S  = ls[0] + ls[2] + ls[4] + ls[6];
        float SS = ls[1] + ls[3] + ls[5] + ls[7];
        const int g = co0 >> 4;
        atomicAdd(&stats[(n * NGROUPS + g) * 2 + 0], S);
        atomicAdd(&stats[(n * NGROUPS + g) * 2 + 1], SS);
    }
}

// ---------------------------------------------------------------------------
// GN normalize + affine + ReLU, float4 vectorized. grid: (HW/4 tiles, C, N)
// ---------------------------------------------------------------------------
__global__ __launch_bounds__(256) void gn_relu_k(
    const float* __restrict__ y, const float* __restrict__ stats,
    const float* __restrict__ gamma, const float* __restrict__ beta,
    float* __restrict__ o, int HW)
{
    const int c = blockIdx.y;
    const int n = blockIdx.z;
    const int p4 = (blockIdx.x * 256 + threadIdx.x) * 4;
    if (p4 >= HW) return;
    const int g = c >> 4;
    const float inv_cnt = 1.0f / (16.0f * (float)HW);
    const float m = stats[(n * NGROUPS + g) * 2 + 0] * inv_cnt;
    const float v = stats[(n * NGROUPS + g) * 2 + 1] * inv_cnt - m * m;
    const float sc = rsqrtf(v + GN_EPS) * gamma[c];
    const float sh = beta[c] - m * sc;
    const size_t base = ((size_t)n * CIN + c) * HW + p4;
    float4 t = *(const float4*)(y + base);
    t.x = fmaxf(t.x * sc + sh, 0.f);
    t.y = fmaxf(t.y * sc + sh, 0.f);
    t.z = fmaxf(t.z * sc + sh, 0.f);
    t.w = fmaxf(t.w * sc + sh, 0.f);
    *(float4*)(o + base) = t;
}

// ---------------------------------------------------------------------------
// Head conv: 3x3 SAME, 256->CO, writes directly into permuted+concat output
// out[n][loff+p][co_out + co] with optional ReLU on channels < relu_cnt.
// ---------------------------------------------------------------------------
__global__ __launch_bounds__(256) void conv_head_k(
    const float* __restrict__ x,     // [N,256,H,W]
    const float* __restrict__ w,     // [CO,256,3,3]
    const float* __restrict__ bias,  // [CO]
    float* __restrict__ out,         // [N,TPOINTS,85]
    int H, int lw, int CO, int co_out, int relu_cnt, int loff)
{
    const int W = 1 << lw;
    const int HW = H << lw;
    const int tid = threadIdx.x;
    const int p = blockIdx.x * 256 + tid;
    const int co0 = blockIdx.y * 4;
    const int n = blockIdx.z;
    if (p >= HW) return;

    const int h = p >> lw;
    const int wc = p & (W - 1);
    const bool tok = h > 0, bok = h < H - 1;
    const bool lok = wc > 0, rok = wc < W - 1;
    const float* xn = x + (size_t)n * CIN * HW + p;
    // clamp weight rows for the tail block (CO=5 case); results discarded
    const float* wr0 = w + (size_t)min(co0 + 0, CO - 1) * (CIN * 9);
    const float* wr1 = w + (size_t)min(co0 + 1, CO - 1) * (CIN * 9);
    const float* wr2 = w + (size_t)min(co0 + 2, CO - 1) * (CIN * 9);
    const float* wr3 = w + (size_t)min(co0 + 3, CO - 1) * (CIN * 9);

    float acc0 = 0.f, acc1 = 0.f, acc2 = 0.f, acc3 = 0.f;
    for (int ci = 0; ci < CIN; ++ci) {
        const float* xc = xn + ci * HW;
        float x00 = (tok & lok) ? xc[-W - 1] : 0.f;
        float x01 = tok ? xc[-W] : 0.f;
        float x02 = (tok & rok) ? xc[-W + 1] : 0.f;
        float x10 = lok ? xc[-1] : 0.f;
        float x11 = xc[0];
        float x12 = rok ? xc[1] : 0.f;
        float x20 = (bok & lok) ? xc[W - 1] : 0.f;
        float x21 = bok ? xc[W] : 0.f;
        float x22 = (bok & rok) ? xc[W + 1] : 0.f;
        const float* w0 = wr0 + ci * 9;
        const float* w1 = wr1 + ci * 9;
        const float* w2 = wr2 + ci * 9;
        const float* w3 = wr3 + ci * 9;
        acc0 += x00*w0[0] + x01*w0[1] + x02*w0[2] + x10*w0[3] + x11*w0[4]
              + x12*w0[5] + x20*w0[6] + x21*w0[7] + x22*w0[8];
        acc1 += x00*w1[0] + x01*w1[1] + x02*w1[2] + x10*w1[3] + x11*w1[4]
              + x12*w1[5] + x20*w1[6] + x21*w1[7] + x22*w1[8];
        acc2 += x00*w2[0] + x01*w2[1] + x02*w2[2] + x10*w2[3] + x11*w2[4]
              + x12*w2[5] + x20*w2[6] + x21*w2[7] + x22*w2[8];
        acc3 += x00*w3[0] + x01*w3[1] + x02*w3[2] + x10*w3[3] + x11*w3[4]
              + x12*w3[5] + x20*w3[6] + x21*w3[7] + x22*w3[8];
    }

    float acc[4] = {acc0, acc1, acc2, acc3};
    const size_t obase = ((size_t)n * TPOINTS + loff + p) * 85 + co_out;
#pragma unroll
    for (int j = 0; j < 4; ++j) {
        const int co = co0 + j;
        if (co < CO) {
            float v = acc[j] + bias[co];
            if (co < relu_cnt) v = fmaxf(v, 0.f);
            out[obase + co] = v;
        }
    }
}

// ---------------------------------------------------------------------------
extern "C" void kernel_launch(void* const* d_in, const int* in_sizes, int n_in,
                              void* d_out, int out_size, void* d_ws, size_t ws_size,
                              hipStream_t stream) {
    const float* feats[5] = {
        (const float*)d_in[0], (const float*)d_in[1], (const float*)d_in[2],
        (const float*)d_in[3], (const float*)d_in[4]};
    const float* cls_w   = (const float*)d_in[5];
    const float* cls_b   = (const float*)d_in[6];
    const float* cls_g   = (const float*)d_in[7];
    const float* cls_be  = (const float*)d_in[8];
    const float* log_w   = (const float*)d_in[9];
    const float* log_b   = (const float*)d_in[10];
    const float* reg_w   = (const float*)d_in[11];
    const float* reg_b   = (const float*)d_in[12];
    const float* reg_g   = (const float*)d_in[13];
    const float* reg_be  = (const float*)d_in[14];
    const float* bbox_w  = (const float*)d_in[15];
    const float* bbox_b  = (const float*)d_in[16];
    const float* ctr_w   = (const float*)d_in[17];
    const float* ctr_b   = (const float*)d_in[18];
    float* out = (float*)d_out;

    // workspace layout
    const size_t MAXBUF = (size_t)2 * CIN * 12800;  // 6,553,600 floats
    float* t0    = (float*)d_ws;
    float* t1    = t0 + MAXBUF;
    float* stats = t1 + MAXBUF;          // 30 slots * 64 floats
    float* hw5   = stats + 30 * 64;      // 5*256*9 concat bbox+ctr weights
    float* hb5   = hw5 + 5 * CIN * 9;    // 5 biases (pad to 8)

    hipMemsetAsync(stats, 0, 30 * 64 * sizeof(float), stream);
    hipMemcpyAsync(hw5,               bbox_w, (size_t)4 * CIN * 9 * 4, hipMemcpyDeviceToDevice, stream);
    hipMemcpyAsync(hw5 + 4 * CIN * 9, ctr_w,  (size_t)CIN * 9 * 4,     hipMemcpyDeviceToDevice, stream);
    hipMemcpyAsync(hb5,     bbox_b, 4 * 4, hipMemcpyDeviceToDevice, stream);
    hipMemcpyAsync(hb5 + 4, ctr_b,  1 * 4, hipMemcpyDeviceToDevice, stream);

    static const int LH[5]  = {100, 50, 25, 13, 7};
    static const int LLW[5] = {7, 6, 5, 4, 3};   // log2(W): 128,64,32,16,8
    static const int LOFF[5] = {0, 12800, 16000, 16800, 17008};

    int slot = 0;
    for (int L = 0; L < 5; ++L) {
        const int H = LH[L], lw = LLW[L];
        const int HW = H << lw;
        const int loff = LOFF[L];
        const int tiles = (HW + 255) / 256;
        const int gtiles = (HW / 4 + 255) / 256;
        dim3 blk(256);

        for (int br = 0; br < 2; ++br) {
            const float* cw = br ? reg_w : cls_w;
            const float* cb = br ? reg_b : cls_b;
            const float* gg = br ? reg_g : cls_g;
            const float* gb = br ? reg_be : cls_be;
            const float* src = feats[L];
            for (int i = 0; i < 3; ++i) {
                float* st = stats + slot * 64;
                ++slot;
                conv_tower_k<<<dim3(tiles, CIN / 4, 2), blk, 0, stream>>>(
                    src, cw + (size_t)i * CIN * CIN * 9, cb + i * CIN, t0, st, H, lw);
                gn_relu_k<<<dim3(gtiles, CIN, 2), blk, 0, stream>>>(
                    t0, st, gg + i * CIN, gb + i * CIN, t1, HW);
                src = t1;
            }
            if (br == 0) {
                conv_head_k<<<dim3(tiles, (NCLS + 3) / 4, 2), blk, 0, stream>>>(
                    t1, log_w, log_b, out, H, lw, NCLS, 0, 0, loff);
            } else {
                conv_head_k<<<dim3(tiles, 2, 2), blk, 0, stream>>>(
                    t1, hw5, hb5, out, H, lw, 5, 80, 4, loff);
            }
        }
    }
}

// Round 5
// 9266.276 us; speedup vs baseline: 1.1461x; 1.1461x over previous
//
#include <hip/hip_runtime.h>

#define CIN 256
#define NGROUPS 16
#define GN_EPS 1e-5f
#define NCLS 80
#define TPOINTS 17064

typedef float v4f __attribute__((ext_vector_type(4)));
typedef short v8s __attribute__((ext_vector_type(8)));

__device__ __forceinline__ unsigned short f2bf(float f) {
    unsigned u = __float_as_uint(f);
    unsigned r = (u + 0x7FFFu + ((u >> 16) & 1u)) >> 16;
    return (unsigned short)r;
}

// LDS row stride in ushorts: 80 B = 5*16 B (keeps ds_read_b128 16B-aligned,
// 16-row walk lands 2-way bank aliased = free per m136)
#define LST 40

// ---------------------------------------------------------------------------
// MFMA tower conv grafted onto the r1 (proven-green) pipeline.
// x: fp32 NCHW [N,256,H,W]; w: fp32 raw [256][256][3][3]; y: fp32 NCHW.
// Tile: 128co x 128pos, 4 waves of 64x64, K = (tap, ci) = 9*256 in 32-chunks.
// Staging: masked scalar fp32 loads -> bf16 -> LDS (correctness-first).
// Epilogue: bias + masked NCHW store + fused GN sum/sumsq (r1 protocol).
// ---------------------------------------------------------------------------
__global__ __launch_bounds__(256) void conv_mfma2_k(
    const float* __restrict__ x, const float* __restrict__ w,
    const float* __restrict__ bias, float* __restrict__ y,
    float* __restrict__ stats, int H, int lw)
{
    const int W = 1 << lw;
    const int HW = H << lw;
    __shared__ unsigned short sA[128 * LST];
    __shared__ unsigned short sB[128 * LST];

    const int tid = threadIdx.x, lane = tid & 63, wave = tid >> 6;
    const int p0 = blockIdx.x * 128, co0 = blockIdx.y * 128, n = blockIdx.z;
    const float* xn = x + (size_t)n * CIN * HW;

    v4f acc[4][4];
#pragma unroll
    for (int i = 0; i < 4; ++i)
#pragma unroll
        for (int j = 0; j < 4; ++j) acc[i][j] = (v4f)0.f;

    const int col = lane & 15, q = lane >> 4;
    const int wco = (wave & 1) * 64, wpos = (wave >> 1) * 64;
    int ard[4], brd[4];
#pragma unroll
    for (int i = 0; i < 4; ++i) {
        ard[i] = (wco  + i * 16 + col) * LST + q * 8;
        brd[i] = (wpos + i * 16 + col) * LST + q * 8;
    }

    for (int t = 0; t < 9; ++t) {
        const int dy = t / 3 - 1, dx = t % 3 - 1;
        const int off = dy * W + dx;
        for (int kb = 0; kb < 8; ++kb) {
            // ---- load A (weights) into regs: A[co][k] = w[co0+co][kb*32+k][t]
            float av[16];
#pragma unroll
            for (int u = 0; u < 16; ++u) {
                const int lin = u * 256 + tid;
                const int aco = lin >> 5, ak = lin & 31;
                av[u] = w[(size_t)(co0 + aco) * 2304 + (kb * 32 + ak) * 9 + t];
            }
            // ---- load B (shifted input) into regs, masked at source
            float bv[4][4];
#pragma unroll
            for (int u = 0; u < 4; ++u) {
                const int lin = u * 256 + tid;
                const int bk = lin >> 5, pq = lin & 31;
                const int p = p0 + pq * 4;           // 4 consecutive pos, same row
                const int h = p >> lw, w0 = p & (W - 1);
                const int hh = h + dy;
                const bool hok = (hh >= 0) & (hh < H) & (p < HW);
                const float* src = xn + (size_t)(kb * 32 + bk) * HW + p + off;
#pragma unroll
                for (int e = 0; e < 4; ++e) {
                    const int ww = w0 + e + dx;
                    bv[u][e] = (hok & (ww >= 0) & (ww < W)) ? src[e] : 0.f;
                }
            }
            __syncthreads();                         // prev frag reads done
#pragma unroll
            for (int u = 0; u < 16; ++u) {
                const int lin = u * 256 + tid;
                const int aco = lin >> 5, ak = lin & 31;
                sA[aco * LST + ak] = f2bf(av[u]);
            }
#pragma unroll
            for (int u = 0; u < 4; ++u) {
                const int lin = u * 256 + tid;
                const int bk = lin >> 5, pq = lin & 31;
#pragma unroll
                for (int e = 0; e < 4; ++e)
                    sB[(pq * 4 + e) * LST + bk] = f2bf(bv[u][e]);
            }
            __syncthreads();                         // stores visible
            v8s af[4], bfr[4];
#pragma unroll
            for (int i = 0; i < 4; ++i) af[i]  = *(const v8s*)&sA[ard[i]];
#pragma unroll
            for (int j = 0; j < 4; ++j) bfr[j] = *(const v8s*)&sB[brd[j]];
#pragma unroll
            for (int i = 0; i < 4; ++i)
#pragma unroll
                for (int j = 0; j < 4; ++j)
                    acc[i][j] = __builtin_amdgcn_mfma_f32_16x16x32_bf16(
                        af[i], bfr[j], acc[i][j], 0, 0, 0);
        }
    }

    // ---- epilogue: bias + masked NCHW fp32 store + fused GN stats
#pragma unroll
    for (int i = 0; i < 4; ++i) {
        const int cobase = co0 + wco + i * 16 + q * 4;
        const float4 b4 = *(const float4*)(bias + cobase);
        float s = 0.f, ss = 0.f;
#pragma unroll
        for (int j = 0; j < 4; ++j) {
            const int p = p0 + wpos + j * 16 + col;
            if (p < HW) {
                float v0 = acc[i][j][0] + b4.x;
                float v1 = acc[i][j][1] + b4.y;
                float v2 = acc[i][j][2] + b4.z;
                float v3 = acc[i][j][3] + b4.w;
                float* yp = y + (size_t)n * CIN * HW + (size_t)cobase * HW + p;
                yp[0]          = v0;
                yp[HW]         = v1;
                yp[2 * (size_t)HW] = v2;
                yp[3 * (size_t)HW] = v3;
                s  += v0 + v1 + v2 + v3;
                ss += v0 * v0 + v1 * v1 + v2 * v2 + v3 * v3;
            }
        }
#pragma unroll
        for (int o = 32; o > 0; o >>= 1) {
            s  += __shfl_down(s, o, 64);
            ss += __shfl_down(ss, o, 64);
        }
        if (lane == 0) {
            const int g = (co0 + wco + i * 16) >> 4;
            atomicAdd(&stats[(n * NGROUPS + g) * 2 + 0], s);
            atomicAdd(&stats[(n * NGROUPS + g) * 2 + 1], ss);
        }
    }
}

// ---------------------------------------------------------------------------
// GN normalize + affine + ReLU, float4 vectorized — r1 VERBATIM (passing).
// ---------------------------------------------------------------------------
__global__ __launch_bounds__(256) void gn_relu_k(
    const float* __restrict__ y, const float* __restrict__ stats,
    const float* __restrict__ gamma, const float* __restrict__ beta,
    float* __restrict__ o, int HW)
{
    const int c = blockIdx.y;
    const int n = blockIdx.z;
    const int p4 = (blockIdx.x * 256 + threadIdx.x) * 4;
    if (p4 >= HW) return;
    const int g = c >> 4;
    const float inv_cnt = 1.0f / (16.0f * (float)HW);
    const float m = stats[(n * NGROUPS + g) * 2 + 0] * inv_cnt;
    const float v = stats[(n * NGROUPS + g) * 2 + 1] * inv_cnt - m * m;
    const float sc = rsqrtf(v + GN_EPS) * gamma[c];
    const float sh = beta[c] - m * sc;
    const size_t base = ((size_t)n * CIN + c) * HW + p4;
    float4 t = *(const float4*)(y + base);
    t.x = fmaxf(t.x * sc + sh, 0.f);
    t.y = fmaxf(t.y * sc + sh, 0.f);
    t.z = fmaxf(t.z * sc + sh, 0.f);
    t.w = fmaxf(t.w * sc + sh, 0.f);
    *(float4*)(o + base) = t;
}

// ---------------------------------------------------------------------------
// Head conv — r1 VERBATIM (passing): 3x3 SAME, 256->CO, permuted/concat write.
// ---------------------------------------------------------------------------
__global__ __launch_bounds__(256) void conv_head_k(
    const float* __restrict__ x, const float* __restrict__ w,
    const float* __restrict__ bias, float* __restrict__ out,
    int H, int lw, int CO, int co_out, int relu_cnt, int loff)
{
    const int W = 1 << lw;
    const int HW = H << lw;
    const int tid = threadIdx.x;
    const int p = blockIdx.x * 256 + tid;
    const int co0 = blockIdx.y * 4;
    const int n = blockIdx.z;
    if (p >= HW) return;

    const int h = p >> lw;
    const int wc = p & (W - 1);
    const bool tok = h > 0, bok = h < H - 1;
    const bool lok = wc > 0, rok = wc < W - 1;
    const float* xn = x + (size_t)n * CIN * HW + p;
    const float* wr0 = w + (size_t)min(co0 + 0, CO - 1) * (CIN * 9);
    const float* wr1 = w + (size_t)min(co0 + 1, CO - 1) * (CIN * 9);
    const float* wr2 = w + (size_t)min(co0 + 2, CO - 1) * (CIN * 9);
    const float* wr3 = w + (size_t)min(co0 + 3, CO - 1) * (CIN * 9);

    float acc0 = 0.f, acc1 = 0.f, acc2 = 0.f, acc3 = 0.f;
    for (int ci = 0; ci < CIN; ++ci) {
        const float* xc = xn + ci * HW;
        float x00 = (tok & lok) ? xc[-W - 1] : 0.f;
        float x01 = tok ? xc[-W] : 0.f;
        float x02 = (tok & rok) ? xc[-W + 1] : 0.f;
        float x10 = lok ? xc[-1] : 0.f;
        float x11 = xc[0];
        float x12 = rok ? xc[1] : 0.f;
        float x20 = (bok & lok) ? xc[W - 1] : 0.f;
        float x21 = bok ? xc[W] : 0.f;
        float x22 = (bok & rok) ? xc[W + 1] : 0.f;
        const float* w0 = wr0 + ci * 9;
        const float* w1 = wr1 + ci * 9;
        const float* w2 = wr2 + ci * 9;
        const float* w3 = wr3 + ci * 9;
        acc0 += x00*w0[0] + x01*w0[1] + x02*w0[2] + x10*w0[3] + x11*w0[4]
              + x12*w0[5] + x20*w0[6] + x21*w0[7] + x22*w0[8];
        acc1 += x00*w1[0] + x01*w1[1] + x02*w1[2] + x10*w1[3] + x11*w1[4]
              + x12*w1[5] + x20*w1[6] + x21*w1[7] + x22*w1[8];
        acc2 += x00*w2[0] + x01*w2[1] + x02*w2[2] + x10*w2[3] + x11*w2[4]
              + x12*w2[5] + x20*w2[6] + x21*w2[7] + x22*w2[8];
        acc3 += x00*w3[0] + x01*w3[1] + x02*w3[2] + x10*w3[3] + x11*w3[4]
              + x12*w3[5] + x20*w3[6] + x21*w3[7] + x22*w3[8];
    }

    float acc[4] = {acc0, acc1, acc2, acc3};
    const size_t obase = ((size_t)n * TPOINTS + loff + p) * 85 + co_out;
#pragma unroll
    for (int j = 0; j < 4; ++j) {
        const int co = co0 + j;
        if (co < CO) {
            float v = acc[j] + bias[co];
            if (co < relu_cnt) v = fmaxf(v, 0.f);
            out[obase + co] = v;
        }
    }
}

// ---------------------------------------------------------------------------
extern "C" void kernel_launch(void* const* d_in, const int* in_sizes, int n_in,
                              void* d_out, int out_size, void* d_ws, size_t ws_size,
                              hipStream_t stream) {
    const float* feats[5] = {
        (const float*)d_in[0], (const float*)d_in[1], (const float*)d_in[2],
        (const float*)d_in[3], (const float*)d_in[4]};
    const float* cls_w   = (const float*)d_in[5];
    const float* cls_b   = (const float*)d_in[6];
    const float* cls_g   = (const float*)d_in[7];
    const float* cls_be  = (const float*)d_in[8];
    const float* log_w   = (const float*)d_in[9];
    const float* log_b   = (const float*)d_in[10];
    const float* reg_w   = (const float*)d_in[11];
    const float* reg_b   = (const float*)d_in[12];
    const float* reg_g   = (const float*)d_in[13];
    const float* reg_be  = (const float*)d_in[14];
    const float* bbox_w  = (const float*)d_in[15];
    const float* bbox_b  = (const float*)d_in[16];
    const float* ctr_w   = (const float*)d_in[17];
    const float* ctr_b   = (const float*)d_in[18];
    float* out = (float*)d_out;

    // workspace layout — r1 VERBATIM
    const size_t MAXBUF = (size_t)2 * CIN * 12800;  // 6,553,600 floats
    float* t0    = (float*)d_ws;
    float* t1    = t0 + MAXBUF;
    float* stats = t1 + MAXBUF;          // 30 slots * 64 floats
    float* hw5   = stats + 30 * 64;      // 5*256*9 concat bbox+ctr weights
    float* hb5   = hw5 + 5 * CIN * 9;    // 5 biases

    hipMemsetAsync(stats, 0, 30 * 64 * sizeof(float), stream);
    hipMemcpyAsync(hw5,               bbox_w, (size_t)4 * CIN * 9 * 4, hipMemcpyDeviceToDevice, stream);
    hipMemcpyAsync(hw5 + 4 * CIN * 9, ctr_w,  (size_t)CIN * 9 * 4,     hipMemcpyDeviceToDevice, stream);
    hipMemcpyAsync(hb5,     bbox_b, 4 * 4, hipMemcpyDeviceToDevice, stream);
    hipMemcpyAsync(hb5 + 4, ctr_b,  1 * 4, hipMemcpyDeviceToDevice, stream);

    static const int LH[5]  = {100, 50, 25, 13, 7};
    static const int LLW[5] = {7, 6, 5, 4, 3};
    static const int LOFF[5] = {0, 12800, 16000, 16800, 17008};

    int slot = 0;
    for (int L = 0; L < 5; ++L) {
        const int H = LH[L], lw = LLW[L];
        const int HW = H << lw;
        const int loff = LOFF[L];
        const int tiles = (HW + 255) / 256;
        const int gtiles = (HW / 4 + 255) / 256;
        const int ctiles = (HW + 127) / 128;
        dim3 blk(256);

        for (int br = 0; br < 2; ++br) {
            const float* cw = br ? reg_w : cls_w;
            const float* cb = br ? reg_b : cls_b;
            const float* gg = br ? reg_g : cls_g;
            const float* gb = br ? reg_be : cls_be;
            const float* src = feats[L];
            for (int i = 0; i < 3; ++i) {
                float* st = stats + slot * 64;
                ++slot;
                conv_mfma2_k<<<dim3(ctiles, 2, 2), blk, 0, stream>>>(
                    src, cw + (size_t)i * CIN * CIN * 9, cb + i * CIN, t0, st, H, lw);
                gn_relu_k<<<dim3(gtiles, CIN, 2), blk, 0, stream>>>(
                    t0, st, gg + i * CIN, gb + i * CIN, t1, HW);
                src = t1;
            }
            if (br == 0) {
                conv_head_k<<<dim3(tiles, (NCLS + 3) / 4, 2), blk, 0, stream>>>(
                    t1, log_w, log_b, out, H, lw, NCLS, 0, 0, loff);
            } else {
                conv_head_k<<<dim3(tiles, 2, 2), blk, 0, stream>>>(
                    t1, hw5, hb5, out, H, lw, 5, 80, 4, loff);
            }
        }
    }
}

// Round 6
// 1456.744 us; speedup vs baseline: 7.2906x; 6.3609x over previous
//
#include <hip/hip_runtime.h>

#define NCLS 80
#define TPOINTS 17064
#define GN_EPS 1e-5f
#define LST 40   // LDS row stride (ushorts): 80B, 16B-aligned, 2-way bank alias = free

typedef float v4f __attribute__((ext_vector_type(4)));
typedef short v8s __attribute__((ext_vector_type(8)));

__device__ __forceinline__ unsigned short f2bf(float f) {
    unsigned u = __float_as_uint(f);
    unsigned r = (u + 0x7FFFu + ((u >> 16) & 1u)) >> 16;
    return (unsigned short)r;
}
__device__ __forceinline__ float bf2f(unsigned short h) {
    return __uint_as_float(((unsigned)h) << 16);
}

struct Lv { int t_conv, t_gn, t_prep, xo, P2W, PP, HW, W, H, lwW, loff; };
struct Tab { Lv lv[5]; };

// ---------------------------------------------------------------------------
// Fused-level implicit-GEMM conv. xin: bf16 NHWC zero-padded, per-level
// regions at lv.xo. wt: bf16 [9][wrows][256]. Tile 128co x 128pos, 4 waves
// of 64x64 (frag/acc mapping identical to r5's proven kernel).
// TOWER (HEAD=0): writes raw bf16 NHWC-padded yout + GN partial stats.
// HEAD  (HEAD=1): writes fp32 into out[n][loff+p][85]+co_out, co<CO masked.
// ---------------------------------------------------------------------------
template<int HEAD>
__global__ __launch_bounds__(256) void conv_k(
    const unsigned short* __restrict__ xin,
    const unsigned short* __restrict__ wt, int wrows,
    const float* __restrict__ bias,
    unsigned short* __restrict__ yout, float* __restrict__ stats, int slot,
    float* __restrict__ out, int CO, int co_out, int relu_cnt,
    Tab tb)
{
    __shared__ unsigned short sA[128 * LST];
    __shared__ unsigned short sB[128 * LST];
    const int tid = threadIdx.x, lane = tid & 63, wave = tid >> 6;
    const int bx = blockIdx.x, n = blockIdx.z;
    int L = 0;
    while (L < 4 && bx >= tb.lv[L + 1].t_conv) ++L;
    const Lv lv = tb.lv[L];
    const int pp0 = (bx - lv.t_conv) * 128;
    const int co0 = HEAD ? 0 : blockIdx.y * 128;

    v4f acc[4][4];
#pragma unroll
    for (int i = 0; i < 4; ++i)
#pragma unroll
        for (int j = 0; j < 4; ++j) acc[i][j] = (v4f)0.f;

    // staging: thread owns 16 ushorts (32B) of each 128x32 tile
    const int srow = tid >> 1;
    const int sch  = (tid & 1) * 16;
    const unsigned short* xb = xin + (size_t)lv.xo + (size_t)n * lv.PP * 256;
    const unsigned short* arow = wt + (size_t)(co0 + srow) * 256 + sch;
    const unsigned short* brow = xb + (size_t)(pp0 + srow) * 256 + sch;
    unsigned short* sAw = &sA[srow * LST + sch];
    unsigned short* sBw = &sB[srow * LST + sch];

    const int col = lane & 15, q = lane >> 4;
    const int wco = (wave & 1) * 64, wpos = (wave >> 1) * 64;
    int ard[4], brd[4];
#pragma unroll
    for (int i = 0; i < 4; ++i) {
        ard[i] = (wco  + i * 16 + col) * LST + q * 8;
        brd[i] = (wpos + i * 16 + col) * LST + q * 8;
    }

    const size_t wstride = (size_t)wrows * 256;
    for (int t = 0; t < 9; ++t) {
        const ptrdiff_t off = ((ptrdiff_t)(t / 3) - 1) * lv.P2W + (t % 3) - 1;
        const unsigned short* at = arow + (size_t)t * wstride;
        const unsigned short* bt = brow + off * 256;
        for (int kb = 0; kb < 8; ++kb) {
            const uint4 a0 = *(const uint4*)(at + kb * 32);
            const uint4 a1 = *(const uint4*)(at + kb * 32 + 8);
            const uint4 b0 = *(const uint4*)(bt + kb * 32);
            const uint4 b1 = *(const uint4*)(bt + kb * 32 + 8);
            __syncthreads();
            *(uint4*)sAw = a0; *(uint4*)(sAw + 8) = a1;
            *(uint4*)sBw = b0; *(uint4*)(sBw + 8) = b1;
            __syncthreads();
            v8s af[4], bfr[4];
#pragma unroll
            for (int i = 0; i < 4; ++i) af[i]  = *(const v8s*)&sA[ard[i]];
#pragma unroll
            for (int j = 0; j < 4; ++j) bfr[j] = *(const v8s*)&sB[brd[j]];
#pragma unroll
            for (int i = 0; i < 4; ++i)
#pragma unroll
                for (int j = 0; j < 4; ++j)
                    acc[i][j] = __builtin_amdgcn_mfma_f32_16x16x32_bf16(
                        af[i], bfr[j], acc[i][j], 0, 0, 0);
        }
    }

    if (!HEAD) {
#pragma unroll
        for (int i = 0; i < 4; ++i) {
            const int cobase = co0 + wco + i * 16 + q * 4;
            const float4 b4 = *(const float4*)(bias + cobase);
            float s = 0.f, ss = 0.f;
#pragma unroll
            for (int j = 0; j < 4; ++j) {
                const int pp = pp0 + wpos + j * 16 + col;
                const unsigned h2 = (unsigned)pp / (unsigned)lv.P2W;
                const unsigned w2 = (unsigned)pp - h2 * lv.P2W;
                const bool in = (h2 >= 1u) & (h2 <= (unsigned)lv.H) &
                                (w2 >= 1u) & (w2 <= (unsigned)lv.W);
                float v0 = acc[i][j][0] + b4.x;
                float v1 = acc[i][j][1] + b4.y;
                float v2 = acc[i][j][2] + b4.z;
                float v3 = acc[i][j][3] + b4.w;
                if (in) {
                    ushort4 pk;
                    pk.x = f2bf(v0); pk.y = f2bf(v1);
                    pk.z = f2bf(v2); pk.w = f2bf(v3);
                    *(ushort4*)(yout + (size_t)lv.xo +
                                ((size_t)n * lv.PP + pp) * 256 + cobase) = pk;
                    s  += v0 + v1 + v2 + v3;
                    ss += v0 * v0 + v1 * v1 + v2 * v2 + v3 * v3;
                }
            }
#pragma unroll
            for (int o = 32; o > 0; o >>= 1) {
                s  += __shfl_down(s, o, 64);
                ss += __shfl_down(ss, o, 64);
            }
            if (lane == 0) {
                const int g = cobase >> 4;
                const int si = (((slot * 5 + L) * 32) + n * 16 + g) * 2;
                atomicAdd(&stats[si + 0], s);
                atomicAdd(&stats[si + 1], ss);
            }
        }
    } else {
#pragma unroll
        for (int i = 0; i < 4; ++i) {
            const int cobase = wco + i * 16 + q * 4;
            float bv[4];
#pragma unroll
            for (int k = 0; k < 4; ++k)
                bv[k] = (cobase + k < CO) ? bias[cobase + k] : 0.f;
#pragma unroll
            for (int j = 0; j < 4; ++j) {
                const int pp = pp0 + wpos + j * 16 + col;
                const unsigned h2 = (unsigned)pp / (unsigned)lv.P2W;
                const unsigned w2 = (unsigned)pp - h2 * lv.P2W;
                const bool in = (h2 >= 1u) & (h2 <= (unsigned)lv.H) &
                                (w2 >= 1u) & (w2 <= (unsigned)lv.W);
                if (in) {
                    const int p = (h2 - 1) * lv.W + (w2 - 1);
                    float* ob = out + ((size_t)n * TPOINTS + lv.loff + p) * 85 + co_out;
#pragma unroll
                    for (int k = 0; k < 4; ++k) {
                        const int co = cobase + k;
                        if (co < CO) {
                            float v = acc[i][j][k] + bv[k];
                            if (co < relu_cnt) v = fmaxf(v, 0.f);
                            ob[co] = v;
                        }
                    }
                }
            }
        }
    }
}

// ---------------------------------------------------------------------------
// GN + affine + ReLU, IN-PLACE on the padded NHWC bf16 buffer (interior only).
// Block = 32 pos x 8 chunks of 32 channels. Fused across levels.
// ---------------------------------------------------------------------------
__global__ __launch_bounds__(256) void gn_k(
    unsigned short* __restrict__ x, const float* __restrict__ stats, int slot,
    const float* __restrict__ gamma, const float* __restrict__ beta, Tab tb)
{
    const int tid = threadIdx.x, bx = blockIdx.x, n = blockIdx.z;
    int L = 0;
    while (L < 4 && bx >= tb.lv[L + 1].t_gn) ++L;
    const Lv lv = tb.lv[L];
    const int pos = (bx - lv.t_gn) * 32 + (tid >> 3);
    if (pos >= lv.HW) return;
    const int c0 = (tid & 7) * 32;
    const int h = pos >> lv.lwW, w = pos & (lv.W - 1);
    const int pp = (h + 1) * lv.P2W + (w + 1);
    unsigned short* p = x + (size_t)lv.xo + ((size_t)n * lv.PP + pp) * 256 + c0;
    const float inv = 1.0f / (16.0f * (float)lv.HW);
    const int sb = ((slot * 5 + L) * 32 + n * 16) * 2;

    float scv[32], shv[32];
#pragma unroll
    for (int gg = 0; gg < 2; ++gg) {
        const int g = (c0 >> 4) + gg;
        const float m = stats[sb + g * 2 + 0] * inv;
        const float v = stats[sb + g * 2 + 1] * inv - m * m;
        const float rs = rsqrtf(v + GN_EPS);
#pragma unroll
        for (int k = 0; k < 16; ++k) {
            const int c = g * 16 + k;
            const float sc = rs * gamma[c];
            scv[gg * 16 + k] = sc;
            shv[gg * 16 + k] = beta[c] - m * sc;
        }
    }
#pragma unroll
    for (int u = 0; u < 4; ++u) {
        uint4 a = *(const uint4*)(p + u * 8);
        unsigned wds[4] = {a.x, a.y, a.z, a.w};
#pragma unroll
        for (int k = 0; k < 4; ++k) {
            const int e = u * 8 + k * 2;
            float lo = bf2f((unsigned short)(wds[k] & 0xffffu));
            float hi = bf2f((unsigned short)(wds[k] >> 16));
            lo = fmaxf(lo * scv[e]     + shv[e],     0.f);
            hi = fmaxf(hi * scv[e + 1] + shv[e + 1], 0.f);
            wds[k] = (unsigned)f2bf(lo) | ((unsigned)f2bf(hi) << 16);
        }
        uint4 o; o.x = wds[0]; o.y = wds[1]; o.z = wds[2]; o.w = wds[3];
        *(uint4*)(p + u * 8) = o;
    }
}

// ---------------------------------------------------------------------------
// fp32 NCHW feats -> bf16 NHWC padded interior (borders pre-zeroed by memset).
// Block = 64 pos x 4 waves (64 channels each). Fused across levels.
// ---------------------------------------------------------------------------
__global__ __launch_bounds__(256) void prepx_k(
    const float* f0, const float* f1, const float* f2, const float* f3,
    const float* f4, unsigned short* __restrict__ xo, Tab tb)
{
    const float* fs[5] = {f0, f1, f2, f3, f4};
    const int tid = threadIdx.x, bx = blockIdx.x, n = blockIdx.z;
    int L = 0;
    while (L < 4 && bx >= tb.lv[L + 1].t_prep) ++L;
    const Lv lv = tb.lv[L];
    const int pos = (bx - lv.t_prep) * 64 + (tid & 63);
    const int wave = tid >> 6;
    if (pos >= lv.HW) return;
    const int h = pos >> lv.lwW, w = pos & (lv.W - 1);
    const int pp = (h + 1) * lv.P2W + (w + 1);
    const float* src = fs[L] + (size_t)n * 256 * lv.HW + pos;
    unsigned short* dst = xo + (size_t)lv.xo + ((size_t)n * lv.PP + pp) * 256;
#pragma unroll
    for (int k = 0; k < 16; ++k) {
        const int c = wave * 64 + k * 4;
        ushort4 pk;
        pk.x = f2bf(src[(size_t)(c + 0) * lv.HW]);
        pk.y = f2bf(src[(size_t)(c + 1) * lv.HW]);
        pk.z = f2bf(src[(size_t)(c + 2) * lv.HW]);
        pk.w = f2bf(src[(size_t)(c + 3) * lv.HW]);
        *(ushort4*)(dst + c) = pk;
    }
}

// ---------------------------------------------------------------------------
// Tower weights fp32 [br][layer][co][ci][3][3] -> bf16 [br][layer][tap][co][ci]
// ---------------------------------------------------------------------------
__global__ __launch_bounds__(256) void prepwt_k(
    const float* __restrict__ cw, const float* __restrict__ rw,
    unsigned short* __restrict__ dst)
{
    const int idx = blockIdx.x * 256 + threadIdx.x;   // 54*65536
    const int ci = idx & 255, co = (idx >> 8) & 255, r = idx >> 16;
    const int tap = r % 9, layer = (r / 9) % 3, br = r / 27;
    const float* s = br ? rw : cw;
    dst[(size_t)r * 65536 + co * 256 + ci] =
        f2bf(s[(((size_t)layer * 256 + co) * 256 + ci) * 9 + tap]);
}

// Head weights fp32 [CO][256][3][3] -> bf16 [9][128][256] (rows roff..roff+CO)
__global__ __launch_bounds__(256) void prepwh_k(
    const float* __restrict__ src, unsigned short* __restrict__ dst,
    int CO, int roff)
{
    const int idx = blockIdx.x * 256 + threadIdx.x;
    if (idx >= CO * 2304) return;
    const int ci = idx & 255, rr = idx >> 8;
    const int tap = rr % 9, co = rr / 9;
    dst[((size_t)tap * 128 + roff + co) * 256 + ci] =
        f2bf(src[((size_t)co * 256 + ci) * 9 + tap]);
}

// ---------------------------------------------------------------------------
extern "C" void kernel_launch(void* const* d_in, const int* in_sizes, int n_in,
                              void* d_out, int out_size, void* d_ws, size_t ws_size,
                              hipStream_t stream) {
    const float* f0 = (const float*)d_in[0];
    const float* f1 = (const float*)d_in[1];
    const float* f2 = (const float*)d_in[2];
    const float* f3 = (const float*)d_in[3];
    const float* f4 = (const float*)d_in[4];
    const float* cls_w  = (const float*)d_in[5];
    const float* cls_b  = (const float*)d_in[6];
    const float* cls_g  = (const float*)d_in[7];
    const float* cls_be = (const float*)d_in[8];
    const float* log_w  = (const float*)d_in[9];
    const float* log_b  = (const float*)d_in[10];
    const float* reg_w  = (const float*)d_in[11];
    const float* reg_b  = (const float*)d_in[12];
    const float* reg_g  = (const float*)d_in[13];
    const float* reg_be = (const float*)d_in[14];
    const float* bbox_w = (const float*)d_in[15];
    const float* bbox_b = (const float*)d_in[16];
    const float* ctr_w  = (const float*)d_in[17];
    const float* ctr_b  = (const float*)d_in[18];
    float* out = (float*)d_out;

    // ---- level table (tiles: conv=ceil(PP/128), gn=ceil(HW/32), prep=ceil(HW/64))
    Tab tb;
    //            t_conv t_gn t_prep xo       P2W  PP     HW     W    H   lwW loff
    tb.lv[0] = {   0,    0,    0,    0,       130, 13260, 12800, 128, 100, 7, 0     };
    tb.lv[1] = { 104,  400,  200,  6789120,    66,  3432,  3200,  64,  50, 6, 12800 };
    tb.lv[2] = { 131,  500,  250,  8546304,    34,   918,   800,  32,  25, 5, 16000 };
    tb.lv[3] = { 139,  525,  263,  9016320,    18,   270,   208,  16,  13, 4, 16800 };
    tb.lv[4] = { 142,  532,  267,  9154560,    10,    90,    56,   8,   7, 3, 17008 };
    const int NT_CONV = 143, NT_GN = 534, NT_PREP = 268;
    const size_t XEL = 9200640;            // total padded elements (both images)

    // ---- workspace layout
    char* base = (char*)d_ws;
    size_t o = 0;
    auto take = [&](size_t bytes) {
        char* p = base + o; o += (bytes + 255) & ~(size_t)255; return p;
    };
    take(262144);                                           // front guard 256KB
    unsigned short* B1 = (unsigned short*)take(XEL * 2);
    take(262144);                                           // guard
    unsigned short* B2 = (unsigned short*)take(XEL * 2);
    take(262144);                                           // back guard
    unsigned short* WT  = (unsigned short*)take((size_t)54 * 65536 * 2);
    unsigned short* WHC = (unsigned short*)take((size_t)9 * 128 * 256 * 2);
    unsigned short* WHR = (unsigned short*)take((size_t)9 * 128 * 256 * 2);
    float* ST  = (float*)take(1920 * 4);
    float* RB5 = (float*)take(32);

    hipMemsetAsync(B1, 0, XEL * 2, stream);
    hipMemsetAsync(B2, 0, XEL * 2, stream);
    hipMemsetAsync(ST, 0, 1920 * 4, stream);
    hipMemcpyAsync(RB5,     bbox_b, 4 * 4, hipMemcpyDeviceToDevice, stream);
    hipMemcpyAsync(RB5 + 4, ctr_b,  1 * 4, hipMemcpyDeviceToDevice, stream);

    prepwt_k<<<dim3(13824), dim3(256), 0, stream>>>(cls_w, reg_w, WT);
    prepwh_k<<<dim3(720), dim3(256), 0, stream>>>(log_w,  WHC, 80, 0);
    prepwh_k<<<dim3(36),  dim3(256), 0, stream>>>(bbox_w, WHR, 4, 0);
    prepwh_k<<<dim3(9),   dim3(256), 0, stream>>>(ctr_w,  WHR, 1, 4);

    const dim3 blk(256);
    for (int br = 0; br < 2; ++br) {
        const unsigned short* wtb = WT + (size_t)br * 27 * 65536;
        const float* cb = br ? reg_b  : cls_b;
        const float* gg = br ? reg_g  : cls_g;
        const float* gb = br ? reg_be : cls_be;

        prepx_k<<<dim3(NT_PREP, 1, 2), blk, 0, stream>>>(f0, f1, f2, f3, f4, B1, tb);

        unsigned short* src = B1;
        unsigned short* dst = B2;
        for (int i = 0; i < 3; ++i) {
            const int slot = br * 3 + i;
            conv_k<0><<<dim3(NT_CONV, 2, 2), blk, 0, stream>>>(
                src, wtb + (size_t)i * 9 * 65536, 256, cb + i * 256,
                dst, ST, slot, nullptr, 0, 0, 0, tb);
            gn_k<<<dim3(NT_GN, 1, 2), blk, 0, stream>>>(
                dst, ST, slot, gg + i * 256, gb + i * 256, tb);
            unsigned short* t = src; src = dst; dst = t;
        }
        // tower output now in `src` (== B2 after 3 swaps)
        if (br == 0)
            conv_k<1><<<dim3(NT_CONV, 1, 2), blk, 0, stream>>>(
                src, WHC, 128, log_b, nullptr, nullptr, 0,
                out, NCLS, 0, 0, tb);
        else
            conv_k<1><<<dim3(NT_CONV, 1, 2), blk, 0, stream>>>(
                src, WHR, 128, RB5, nullptr, nullptr, 0,
                out, 5, 80, 4, tb);
    }
}